// Round 4
// baseline (954.889 us; speedup 1.0000x reference)
//
#include <hip/hip_runtime.h>

// Dims: B=16, H=W=64, C_OUT=64, C_IN=32, S(n_out)=10, 3x3 SAME conv adjoint.
// Input  w_out[b, 0, (h*64+w)*64+co, s] : per (b,pixel) contiguous 640 fp32 (co major, s minor)
// Output w_new[b, 0, (h*64+w)*32+ci, s] : per (b,pixel) contiguous 320 fp32 (ci major, s minor)
// y[b,s,h,w,ci] = sum_{i,j,co} z[b,s,h+1-i,w+1-j,co] * K[i,j,ci,co]
//
// Round-4: MFMA rewrite. Per tap this is a GEMM: D[ci=32][slot n=w*10+s] +=
// K[ci][co] * z[n + 10*(1-j), row h-1+r][co], done with mfma_f32_32x32x16_bf16.
// z is split z = z_hi + z_lo (two bf16 planes, two fp32 acc chains, summed at
// store) so numerics stay dominated by the same K-bf16 quantization as all
// previous passing rounds. K fragments are register-resident (from L2).
// Block = (set,b,h), 320 thr = 5 waves; 4 w-quarters x 4 co-chunks stages.

typedef unsigned int uint;
typedef unsigned short ushort;
typedef __attribute__((ext_vector_type(8))) short bf16x8;
typedef __attribute__((ext_vector_type(16))) float f32x16;

#define OUT_BU_OFF 20971520u   // 16*131072*10  (fp32 elements)
#define OUT_WL_OFF 20971680u
#define OUT_BL_OFF 41943200u
#define IN_PER_B   2621440u    // 4096*640 (fp32 elements)

__device__ __forceinline__ ushort f2bf(float f) {
    uint x = __float_as_uint(f);
    x += 0x7fffu + ((x >> 16) & 1u);   // RNE
    return (ushort)(x >> 16);
}
__device__ __forceinline__ float bfh2f(ushort h) { return __uint_as_float(((uint)h) << 16); }

// grid: 2048 = 2 sets * 16 b * 64 h ; block: 320 = 5 waves
__global__ __launch_bounds__(320) void conv_kernel(
    const float* __restrict__ inU, const float* __restrict__ inL,
    const float* __restrict__ Kg, const float* __restrict__ bias,
    float* __restrict__ out, float* __restrict__ ws)
{
    // z tile: [r(3)][slot L(180)][40 ushorts = 16 hi | 16 lo | 8 pad] = 43,200 B
    // pitch 80 B -> 8 distinct bank-start positions on strided b128 reads.
    __shared__ ushort zlds[3 * 180 * 40];
    __shared__ float  red[64];           // 5 waves x 10 bias partials

    const int tid = threadIdx.x;
    // XCD-aware bijective swizzle (2048 % 8 == 0)
    const int blk = (int)((blockIdx.x & 7) * 256 + (blockIdx.x >> 3));
    const int h   = blk & 63;
    const int b   = (blk >> 6) & 15;
    const int set = blk >> 10;

    const float* in   = set ? inL : inU;
    float*       outw = out + (set ? OUT_WL_OFF : 0u);
    const float* inb  = in + (size_t)b * IN_PER_B;

    const int lane = tid & 63;
    const int wv   = tid >> 6;        // 0..4 : n-tile within quarter
    const int ln31 = lane & 31;
    const int half = lane >> 5;       // k-half (8 co)

    // staging decomposition: 216 units = r(3) x u(18 w incl +-1 halo) x co-quad(4)
    const int  sr      = tid / 72;
    const int  rem     = tid - sr * 72;
    const int  su      = rem >> 2;    // 0..17
    const int  scq     = rem & 3;     // co-quad
    const bool sactive = tid < 216;
    const int  ssh     = h - 1 + sr;  // staged global row

    float bacc[10];
#pragma unroll
    for (int s = 0; s < 10; ++s) bacc[s] = 0.f;

#pragma unroll 1
    for (int q = 0; q < 4; ++q) {
        f32x16 acc_h, acc_l;
#pragma unroll
        for (int e = 0; e < 16; ++e) { acc_h[e] = 0.f; acc_l[e] = 0.f; }

#pragma unroll 1
        for (int c = 0; c < 4; ++c) {
            __syncthreads();   // previous stage's LDS reads done

            // ---------------- stage z (+ fused exact-fp32 bias) ----------------
            if (sactive) {
                const int w   = q * 16 - 1 + su;
                const int co0 = c * 16 + scq * 4;
                ushort* dst = &zlds[(sr * 180 + su * 10) * 40 + scq * 4];
                if ((unsigned)w >= 64u) {
#pragma unroll
                    for (int s = 0; s < 10; ++s) {
                        *(uint2*)&dst[s * 40]      = make_uint2(0u, 0u);
                        *(uint2*)&dst[s * 40 + 16] = make_uint2(0u, 0u);
                    }
                } else if ((unsigned)ssh < 64u) {
                    const float* p = inb + (size_t)(ssh * 64 + w) * 640u;
                    float zv[4][10];
#pragma unroll
                    for (int cc = 0; cc < 4; ++cc) {
                        const float* pc = p + (co0 + cc) * 10;   // 8B-aligned
                        float2 a0 = *(const float2*)pc;
                        float2 a1 = *(const float2*)(pc + 2);
                        float2 a2 = *(const float2*)(pc + 4);
                        float2 a3 = *(const float2*)(pc + 6);
                        float2 a4 = *(const float2*)(pc + 8);
                        zv[cc][0] = a0.x; zv[cc][1] = a0.y;
                        zv[cc][2] = a1.x; zv[cc][3] = a1.y;
                        zv[cc][4] = a2.x; zv[cc][5] = a2.y;
                        zv[cc][6] = a3.x; zv[cc][7] = a3.y;
                        zv[cc][8] = a4.x; zv[cc][9] = a4.y;
                    }
                    // bias: center row only (r==1 <=> global row h), non-halo w,
                    // exact fp32 z -> same numerics as previous rounds.
                    if (sr == 1 && su >= 1 && su <= 16) {
#pragma unroll
                        for (int cc = 0; cc < 4; ++cc) {
                            const float bf = bias[co0 + cc];
#pragma unroll
                            for (int s = 0; s < 10; ++s) bacc[s] += zv[cc][s] * bf;
                        }
                    }
#pragma unroll
                    for (int s = 0; s < 10; ++s) {
                        ushort h0 = f2bf(zv[0][s]), h1 = f2bf(zv[1][s]);
                        ushort h2 = f2bf(zv[2][s]), h3 = f2bf(zv[3][s]);
                        ushort g0 = f2bf(zv[0][s] - bfh2f(h0));
                        ushort g1 = f2bf(zv[1][s] - bfh2f(h1));
                        ushort g2 = f2bf(zv[2][s] - bfh2f(h2));
                        ushort g3 = f2bf(zv[3][s] - bfh2f(h3));
                        *(uint2*)&dst[s * 40] =
                            make_uint2((uint)h0 | ((uint)h1 << 16), (uint)h2 | ((uint)h3 << 16));
                        *(uint2*)&dst[s * 40 + 16] =
                            make_uint2((uint)g0 | ((uint)g1 << 16), (uint)g2 | ((uint)g3 << 16));
                    }
                }
            }
            __syncthreads();   // tile ready

            // ---------------- K fragments (registers, from L2) ----------------
            // A[m=ci=ln31][k = half*8 + 0..7] for each of 9 taps.
            bf16x8 kf[9];
#pragma unroll
            for (int t = 0; t < 9; ++t) {
                const float* kp = Kg + t * 2048 + ln31 * 64 + c * 16 + half * 8;  // 16B-aligned
                float4 A  = *(const float4*)kp;
                float4 Bv = *(const float4*)(kp + 4);
                bf16x8 kv;
                kv[0] = (short)f2bf(A.x);  kv[1] = (short)f2bf(A.y);
                kv[2] = (short)f2bf(A.z);  kv[3] = (short)f2bf(A.w);
                kv[4] = (short)f2bf(Bv.x); kv[5] = (short)f2bf(Bv.y);
                kv[6] = (short)f2bf(Bv.z); kv[7] = (short)f2bf(Bv.w);
                kf[t] = kv;
            }

            // ---------------- MFMA sweep: 9 taps x {hi,lo} ----------------
#pragma unroll
            for (int i = 0; i < 3; ++i) {
                if ((unsigned)(h + 1 - i) < 64u) {
                    const int r = 2 - i;
                    const ushort* rowp = &zlds[r * 7200 + half * 8];
#pragma unroll
                    for (int j = 0; j < 3; ++j) {
                        // B col n(lane)=ln31 within tile; tap shift = +10*(1-j) slots
                        const int Lb = 10 + wv * 32 + 10 * (1 - j) + ln31;
                        const ushort* sp = rowp + Lb * 40;           // 16B-aligned
                        uint4 uh = *(const uint4*)sp;                // hi plane
                        uint4 ul = *(const uint4*)(sp + 16);         // lo plane
                        acc_h = __builtin_amdgcn_mfma_f32_32x32x16_bf16(
                            kf[i * 3 + j], __builtin_bit_cast(bf16x8, uh), acc_h, 0, 0, 0);
                        acc_l = __builtin_amdgcn_mfma_f32_32x32x16_bf16(
                            kf[i * 3 + j], __builtin_bit_cast(bf16x8, ul), acc_l, 0, 0, 0);
                    }
                }
            }
        } // c

        // ---------------- store quarter: D[ci][slot], slot per lane ----------------
        const int n  = q * 160 + wv * 32 + ln31;     // 0..639
        const int pw = n / 10;
        const int ps = n - pw * 10;
        float* ob = outw + (size_t)b * 1310720u + (size_t)(h * 64 + pw) * 320u + (size_t)ps;
#pragma unroll
        for (int reg = 0; reg < 16; ++reg) {
            const int ci = (reg & 3) + 8 * (reg >> 2) + 4 * half;
            ob[ci * 10] = acc_h[reg] + acc_l[reg];
        }
    } // q

    // ---------------- bias block-reduction ----------------
#pragma unroll
    for (int s = 0; s < 10; ++s) {
        float v = bacc[s];
        v += __shfl_xor(v, 32, 64);
        v += __shfl_xor(v, 16, 64);
        v += __shfl_xor(v, 8, 64);
        v += __shfl_xor(v, 4, 64);
        v += __shfl_xor(v, 2, 64);
        v += __shfl_xor(v, 1, 64);
        if (lane == 0) red[wv * 10 + s] = v;
    }
    __syncthreads();
    if (tid < 10) {
        float t = red[tid] + red[10 + tid] + red[20 + tid] + red[30 + tid] + red[40 + tid];
        atomicAdd(&ws[(set * 16 + b) * 10 + tid], t);
    }
}

// ---------------- epilogue: add b_out, write fp32 ----------------
__global__ __launch_bounds__(320) void final_bias(
    const float* __restrict__ ws, const float* __restrict__ bU,
    const float* __restrict__ bL, float* __restrict__ out)
{
    const int i = threadIdx.x;
    if (i >= 320) return;
    const int set = i / 160;
    const int r   = i - set * 160;
    const float* bin = set ? bL : bU;
    out[(set ? OUT_BL_OFF : OUT_BU_OFF) + r] = ws[i] + bin[r];
}

extern "C" void kernel_launch(void* const* d_in, const int* in_sizes, int n_in,
                              void* d_out, int out_size, void* d_ws, size_t ws_size,
                              hipStream_t stream) {
    const float* wU   = (const float*)d_in[0];
    const float* bU   = (const float*)d_in[1];
    const float* wL   = (const float*)d_in[2];
    const float* bL   = (const float*)d_in[3];
    const float* Kg   = (const float*)d_in[4];
    const float* bias = (const float*)d_in[5];
    float* out = (float*)d_out;
    float* ws  = (float*)d_ws;

    hipMemsetAsync(ws, 0, 320 * sizeof(float), stream);
    hipLaunchKernelGGL(conv_kernel, dim3(2048), dim3(320), 0, stream,
                       wU, wL, Kg, bias, out, ws);
    hipLaunchKernelGGL(final_bias, dim3(1), dim3(320), 0, stream, ws, bU, bL, out);
}

// Round 5
// 550.841 us; speedup vs baseline: 1.7335x; 1.7335x over previous
//
#include <hip/hip_runtime.h>

// Dims: B=16, H=W=64, C_OUT=64, C_IN=32, S(n_out)=10, 3x3 SAME conv adjoint.
// Input  w_out[b, 0, (h*64+w)*64+co, s] : per (b,pixel) contiguous 640 fp32 (co major, s minor)
// Output w_new[b, 0, (h*64+w)*32+ci, s] : per (b,pixel) contiguous 320 fp32 (ci major, s minor)
// y[b,s,h,w,ci] = sum_{i,j,co} z[b,s,h+1-i,w+1-j,co] * K[i,j,ci,co]
//
// Round-5: MFMA with hi/lo-in-k packing (kappa = 2*co+plane, K duplicated in A,
// z split into truncated bf16 hi + bf16(v-hi) planes => ONE acc chain, repr err
// ~2^-16 rel, far below the K-bf16 quantization all passing rounds carry).
// Stage = (co-chunk of 8, input row r): 24 single-row stages, double-buffered
// LDS (63.4 KB -> 2 blocks/CU), reg-prefetch z 2 stages ahead + K 1 stage
// ahead, ONE barrier per stage (round-3's proven T14 pattern).
// Per wave: 4 n-tiles of 32 slots (acc 64 VGPR); z staged once per block.

typedef unsigned int uint;
typedef unsigned short ushort;
typedef __attribute__((ext_vector_type(8))) short bf16x8;
typedef __attribute__((ext_vector_type(16))) float f32x16;

#define OUT_BU_OFF 20971520u   // 16*131072*10  (fp32 elements)
#define OUT_WL_OFF 20971680u
#define OUT_BL_OFF 41943200u
#define IN_PER_B   2621440u    // 4096*640 (fp32 elements)

__device__ __forceinline__ ushort f2bf(float f) {   // RNE (K only, matches prior rounds)
    uint x = __float_as_uint(f);
    x += 0x7fffu + ((x >> 16) & 1u);
    return (ushort)(x >> 16);
}

// grid: 2048 = 2 sets * 16 b * 64 h ; block: 320 = 5 waves
__global__ __launch_bounds__(320) void conv_kernel(
    const float* __restrict__ inU, const float* __restrict__ inL,
    const float* __restrict__ Kg, const float* __restrict__ bias,
    float* __restrict__ out, float* __restrict__ ws)
{
    // z row-stage: [buf][slot L 0..659][12 dwords: 8 data (16 ushort kappa) + 4 pad]
    // pitch 12 dwords: consecutive-8-lane b128 reads cover all 32 banks exactly
    // once (starts {0,12,24,4,16,28,8,20}) -> conflict-free.
    __shared__ uint  zbuf[2 * 7920];     // 63,360 B
    __shared__ float red[50];

    const int tid = threadIdx.x;
    // XCD-aware bijective swizzle (2048 % 8 == 0)
    const int blk = (int)((blockIdx.x & 7) * 256 + (blockIdx.x >> 3));
    const int h   = blk & 63;
    const int b   = (blk >> 6) & 15;
    const int set = blk >> 10;

    const float* in   = set ? inL : inU;
    float*       outw = out + (set ? OUT_WL_OFF : 0u);
    const float* inb  = in + (size_t)b * IN_PER_B;

    const int lane  = tid & 63;
    const int wv    = tid >> 6;       // 0..4
    const int ln31  = lane & 31;
    const int half  = lane >> 5;
    const int half4 = half * 4;

    // staging units: 512 = 64 w x 8 co_sub; u0 = tid, u1 = tid+320 (tid<192)
    const int  w0  = tid >> 3;        // 0..39
    const int  cs  = tid & 7;
    const bool u1e = (tid < 192);
    const int  go0 = w0 * 640 + cs * 10;
    const int  go1 = go0 + 40 * 640;                 // w = w0+40
    const int  lw0 = (10 + w0 * 10) * 12 + cs;       // + s*12
    const int  lw1 = lw0 + 400 * 12;

    // zero halo pads (rows L 0..9 and 650..659, both buffers) — written once
    for (int d = tid; d < 480; d += 320) {
        int bi = d / 240, k = d - bi * 240;
        int dw = (k < 120) ? k : (7800 + k - 120);
        zbuf[bi * 7920 + dw] = 0u;
    }

    const int rlo = (h == 0) ? 1 : 0;
    const int rhi = (h == 63) ? 1 : 2;
    const int NS  = 8 * (rhi - rlo + 1);

    float va[10], vb[10];
    float bacc[10];
#pragma unroll
    for (int s = 0; s < 10; ++s) bacc[s] = 0.f;

    f32x16 acc0, acc1, acc2, acc3;
#pragma unroll
    for (int e = 0; e < 16; ++e) { acc0[e] = 0.f; acc1[e] = 0.f; acc2[e] = 0.f; acc3[e] = 0.f; }

    int c0 = 0, r0 = rlo;     // compute stage t
    int c1 = 0, r1 = rlo;     // store stage  t+1
    int c2 = 0, r2 = rlo;     // load stage   t+2

#define ADV(C, R) do { if (++(R) > rhi) { (R) = rlo; ++(C); } } while (0)

#define LOADV(CC, RR) do { \
        const float* p_ = inb + (size_t)((h - 1 + (RR)) * 64) * 640u + (CC) * 80; \
        const float* q0_ = p_ + go0; \
        _Pragma("unroll") for (int k_ = 0; k_ < 5; ++k_) { \
            float2 t_ = *(const float2*)(q0_ + 2 * k_); va[2*k_] = t_.x; va[2*k_+1] = t_.y; } \
        if (u1e) { const float* q1_ = p_ + go1; \
            _Pragma("unroll") for (int k_ = 0; k_ < 5; ++k_) { \
                float2 t_ = *(const float2*)(q1_ + 2 * k_); vb[2*k_] = t_.x; vb[2*k_+1] = t_.y; } } \
    } while (0)

    // trunc hi/lo split: hi = chop-to-bf16(v) (exact in fp32), lo = trunc(v-hi)
#define STOREV(CC, RR, BUF) do { \
        uint* zb_ = &zbuf[(BUF) * 7920]; \
        if ((RR) == 1) { const float bf_ = bias[(CC) * 8 + cs]; \
            _Pragma("unroll") for (int s_ = 0; s_ < 10; ++s_) { \
                bacc[s_] += va[s_] * bf_; if (u1e) bacc[s_] += vb[s_] * bf_; } } \
        _Pragma("unroll") for (int s_ = 0; s_ < 10; ++s_) { \
            uint x_ = __float_as_uint(va[s_]); \
            float h_ = __uint_as_float(x_ & 0xffff0000u); \
            uint xl_ = __float_as_uint(va[s_] - h_); \
            zb_[lw0 + s_ * 12] = (x_ >> 16) | (xl_ & 0xffff0000u); } \
        if (u1e) { _Pragma("unroll") for (int s_ = 0; s_ < 10; ++s_) { \
            uint x_ = __float_as_uint(vb[s_]); \
            float h_ = __uint_as_float(x_ & 0xffff0000u); \
            uint xl_ = __float_as_uint(vb[s_] - h_); \
            zb_[lw1 + s_ * 12] = (x_ >> 16) | (xl_ & 0xffff0000u); } } \
    } while (0)

#define MFMAQ(ACCV, QI) do { \
        uint4 bb_ = *(const uint4*)&zb[(Lb + 32 * (QI)) * 12 + half4]; \
        ACCV = __builtin_amdgcn_mfma_f32_32x32x16_bf16( \
            kv, __builtin_bit_cast(bf16x8, bb_), ACCV, 0, 0, 0); \
    } while (0)

    ADV(c1, r1);
    ADV(c2, r2); ADV(c2, r2);

    // K fragments for stage 0 (one float4 per tap-col; kappa-duplicated at use)
    float4 kcu[3], knx[3];
    {
        const int i0 = 2 - r0;
#pragma unroll
        for (int j = 0; j < 3; ++j)
            kcu[j] = *(const float4*)(Kg + (i0 * 3 + j) * 2048 + ln31 * 64 + c0 * 8 + half4);
    }

    LOADV(c0, r0);
    STOREV(c0, r0, 0);
    LOADV(c1, r1);
    __syncthreads();            // buf0 + pads ready

#pragma unroll 1
    for (int t = 0; t < NS; ++t) {
        const int cur = t & 1;
        if (t + 1 < NS) {
            // K prefetch for stage t+1 (earliest issue)
            const int i1 = 2 - r1;
#pragma unroll
            for (int j = 0; j < 3; ++j)
                knx[j] = *(const float4*)(Kg + (i1 * 3 + j) * 2048 + ln31 * 64 + c1 * 8 + half4);
            STOREV(c1, r1, cur ^ 1);      // buf^1 last read at t-1; barrier protects
            if (t + 2 < NS) LOADV(c2, r2);
        }

        const uint* zb = &zbuf[cur * 7920];
#pragma unroll
        for (int j = 0; j < 3; ++j) {
            const float4 kf4 = kcu[j];
            const ushort b0_ = f2bf(kf4.x), b1_ = f2bf(kf4.y),
                         b2_ = f2bf(kf4.z), b3_ = f2bf(kf4.w);
            bf16x8 kv;
            kv[0] = (short)b0_; kv[1] = (short)b0_;
            kv[2] = (short)b1_; kv[3] = (short)b1_;
            kv[4] = (short)b2_; kv[5] = (short)b2_;
            kv[6] = (short)b3_; kv[7] = (short)b3_;
            const int Lb = 10 * (2 - j) + wv * 128 + ln31;
            MFMAQ(acc0, 0);
            MFMAQ(acc1, 1);
            MFMAQ(acc2, 2);
            MFMAQ(acc3, 3);
        }
        __syncthreads();
        kcu[0] = knx[0]; kcu[1] = knx[1]; kcu[2] = knx[2];
        ADV(c0, r0); ADV(c1, r1); ADV(c2, r2);
    }

    // ---- store: D col = slot n (lane), row = ci = (reg&3)+8*(reg>>2)+4*half ----
#define STQ(ACCV, N) do { \
        const int pw_ = (N) / 10, ps_ = (N) - pw_ * 10; \
        float* ob_ = outw + (size_t)b * 1310720u + (size_t)(h * 64 + pw_) * 320u + (size_t)ps_; \
        _Pragma("unroll") for (int rg_ = 0; rg_ < 16; ++rg_) { \
            const int ci_ = (rg_ & 3) + 8 * (rg_ >> 2) + 4 * half; \
            ob_[ci_ * 10] = (ACCV)[rg_]; } \
    } while (0)

    const int nb = wv * 128 + ln31;
    STQ(acc0, nb);
    STQ(acc1, nb + 32);
    STQ(acc2, nb + 64);
    STQ(acc3, nb + 96);

    // ---- bias block-reduction ----
#pragma unroll
    for (int s = 0; s < 10; ++s) {
        float v = bacc[s];
        v += __shfl_xor(v, 32, 64);
        v += __shfl_xor(v, 16, 64);
        v += __shfl_xor(v, 8, 64);
        v += __shfl_xor(v, 4, 64);
        v += __shfl_xor(v, 2, 64);
        v += __shfl_xor(v, 1, 64);
        if (lane == 0) red[wv * 10 + s] = v;
    }
    __syncthreads();
    if (tid < 10) {
        float t = red[tid] + red[10 + tid] + red[20 + tid] + red[30 + tid] + red[40 + tid];
        atomicAdd(&ws[(set * 16 + b) * 10 + tid], t);
    }
#undef ADV
#undef LOADV
#undef STOREV
#undef MFMAQ
#undef STQ
}

// ---------------- epilogue: add b_out, write fp32 ----------------
__global__ __launch_bounds__(320) void final_bias(
    const float* __restrict__ ws, const float* __restrict__ bU,
    const float* __restrict__ bL, float* __restrict__ out)
{
    const int i = threadIdx.x;
    if (i >= 320) return;
    const int set = i / 160;
    const int r   = i - set * 160;
    const float* bin = set ? bL : bU;
    out[(set ? OUT_BL_OFF : OUT_BU_OFF) + r] = ws[i] + bin[r];
}

extern "C" void kernel_launch(void* const* d_in, const int* in_sizes, int n_in,
                              void* d_out, int out_size, void* d_ws, size_t ws_size,
                              hipStream_t stream) {
    const float* wU   = (const float*)d_in[0];
    const float* bU   = (const float*)d_in[1];
    const float* wL   = (const float*)d_in[2];
    const float* bL   = (const float*)d_in[3];
    const float* Kg   = (const float*)d_in[4];
    const float* bias = (const float*)d_in[5];
    float* out = (float*)d_out;
    float* ws  = (float*)d_ws;

    hipMemsetAsync(ws, 0, 320 * sizeof(float), stream);
    hipLaunchKernelGGL(conv_kernel, dim3(2048), dim3(320), 0, stream,
                       wU, wL, Kg, bias, out, ws);
    hipLaunchKernelGGL(final_bias, dim3(1), dim3(320), 0, stream, ws, bU, bL, out);
}